// Round 4
// baseline (361.535 us; speedup 1.0000x reference)
//
#include <hip/hip_runtime.h>
#include <hip/hip_bf16.h>
#include <math.h>

#define B 64
#define CIN 96
#define HH 28
#define WW 28
#define NPIX 784
#define E 4
#define HID 576
#define RED 24
#define RHID 24
#define COUT 96
#define EPS 1e-3f

typedef __attribute__((ext_vector_type(8))) short short8v;
typedef __attribute__((ext_vector_type(4))) float f32x4;

__device__ __forceinline__ float sigmoidf_(float v) { return 1.0f / (1.0f + __expf(-v)); }

__device__ __forceinline__ unsigned short f2bf(float v) {
    __hip_bfloat16 h = __float2bfloat16(v);
    return *reinterpret_cast<unsigned short*>(&h);
}

__device__ __forceinline__ float bf2f(unsigned short u) {
    unsigned int w = ((unsigned int)u) << 16;
    return *reinterpret_cast<float*>(&w);
}

// ---------------- K1a: pool[b][c] = mean over pixels; one wave per (b,c) row ----------------
__global__ __launch_bounds__(256) void k_pool(const float* __restrict__ x, float* __restrict__ pool) {
    int row = blockIdx.x * 4 + (threadIdx.x >> 6);  // b*CIN + c  (0..6143)
    int lane = threadIdx.x & 63;
    const float4* xr = reinterpret_cast<const float4*>(x + (size_t)row * NPIX);  // 196 float4
    float s = 0.f;
    for (int i = lane; i < 196; i += 64) {
        float4 v = xr[i];
        s += v.x + v.y + v.z + v.w;
    }
#pragma unroll
    for (int off = 32; off > 0; off >>= 1) s += __shfl_down(s, off);
    if (lane == 0) pool[row] = s * (1.0f / NPIX);
}

// ---------------- K1b: MLP + softmax for all samples; 1 block, thread t = sample t ----------------
__global__ __launch_bounds__(256) void k_mlp(const float* __restrict__ pool,
                                             const float* __restrict__ r_w1, const float* __restrict__ r_b1,
                                             const float* __restrict__ r_w2, const float* __restrict__ r_b2,
                                             float* __restrict__ rw) {
    __shared__ float w1[RHID * CIN];
    __shared__ float b1s[RHID];
    __shared__ float w2[E * RHID];
    __shared__ float b2s[E];
    __shared__ float pl[B * CIN];
    int tid = threadIdx.x;
    for (int i = tid; i < RHID * CIN; i += 256) w1[i] = r_w1[i];
    if (tid < RHID) b1s[tid] = r_b1[tid];
    if (tid < E * RHID) w2[tid] = r_w2[tid];
    if (tid < E) b2s[tid] = r_b2[tid];
    for (int i = tid; i < B * CIN; i += 256) pl[i] = pool[i];
    __syncthreads();
    if (tid < B) {
        const float* p = pl + tid * CIN;
        float hdn[RHID];
#pragma unroll
        for (int r = 0; r < RHID; ++r) {
            float a = b1s[r];
            for (int c = 0; c < CIN; ++c) a += p[c] * w1[r * CIN + c];
            hdn[r] = fmaxf(a, 0.f);
        }
        float lg[E];
        float mx = -1e30f;
#pragma unroll
        for (int e = 0; e < E; ++e) {
            float a = b2s[e];
#pragma unroll
            for (int r = 0; r < RHID; ++r) a += hdn[r] * w2[e * RHID + r];
            lg[e] = a;
            mx = fmaxf(mx, a);
        }
        float den = 0.f;
#pragma unroll
        for (int e = 0; e < E; ++e) { lg[e] = __expf(lg[e] - mx); den += lg[e]; }
#pragma unroll
        for (int e = 0; e < E; ++e) rw[tid * E + e] = lg[e] / den;
    }
}

// ---------------- K2b: exp_w -> bf16 ----------------
__global__ void k_wcvt(const float* __restrict__ w, unsigned short* __restrict__ wb) {
    int i = blockIdx.x * blockDim.x + threadIdx.x;
    if (i < HID * CIN) wb[i] = f2bf(w[i]);
}

// ---------------- K3: expand GEMM (MFMA bf16) + BN1 + SiLU -> hid (bf16 [b][c][p]) ----------------
__global__ __launch_bounds__(256) void k_expand_mfma(
    const float* __restrict__ x, const unsigned short* __restrict__ w_bf,  // [576][96] bf16
    const float* __restrict__ bn1_g, const float* __restrict__ bn1_b,
    const float* __restrict__ bn1_m, const float* __restrict__ bn1_v,
    __hip_bfloat16* __restrict__ hid) {
    int nc = blockIdx.x;  // 0..6
    int b = blockIdx.y;
    int tid = threadIdx.x;
    int lane = tid & 63, wv = tid >> 6;
    int col = lane & 15, g = lane >> 4;
    __shared__ unsigned short xt[96 * 116];  // [k=96][px=112 pad 116] bf16
    __shared__ float inv1s[HID], sh1s[HID];

    for (int i = tid; i < HID; i += 256) {
        float inv = bn1_g[i] * rsqrtf(bn1_v[i] + EPS);
        inv1s[i] = inv;
        sh1s[i] = bn1_b[i] - bn1_m[i] * inv;
    }
    const float* xb = x + (size_t)b * CIN * NPIX + nc * 112;
    for (int i = tid; i < 96 * 28; i += 256) {
        int c = i / 28, q = i % 28;
        float4 v = *reinterpret_cast<const float4*>(&xb[c * NPIX + q * 4]);
        ushort4 s;
        s.x = f2bf(v.x); s.y = f2bf(v.y); s.z = f2bf(v.z); s.w = f2bf(v.w);
        *reinterpret_cast<ushort4*>(&xt[c * 116 + q * 4]) = s;
    }
    __syncthreads();

    const short8v* wv8 = reinterpret_cast<const short8v*>(w_bf);
    for (int nf = 0; nf < 7; ++nf) {
        int pcol = nf * 16 + col;
        short8v bfr[3];
#pragma unroll
        for (int kk = 0; kk < 3; ++kk) {
            int k0 = kk * 32 + 8 * g;
#pragma unroll
            for (int j = 0; j < 8; ++j) bfr[kk][j] = (short)xt[(k0 + j) * 116 + pcol];
        }
        int px = nc * 112 + pcol;
#pragma unroll
        for (int mi = 0; mi < 9; ++mi) {
            int mb = (wv * 9 + mi) * 16;
            f32x4 acc = {0.f, 0.f, 0.f, 0.f};
#pragma unroll
            for (int kk = 0; kk < 3; ++kk) {
                short8v af = wv8[((mb + col) * 96 + kk * 32 + 8 * g) >> 3];
                acc = __builtin_amdgcn_mfma_f32_16x16x32_bf16(af, bfr[kk], acc, 0, 0, 0);
            }
#pragma unroll
            for (int r = 0; r < 4; ++r) {
                int oc = mb + 4 * g + r;
                float t = acc[r] * inv1s[oc] + sh1s[oc];
                float u = t * sigmoidf_(t);
                hid[((size_t)b * HID + oc) * NPIX + px] = __float2bfloat16(u);
            }
        }
    }
}

// ---------------- K4: depthwise 5x5, padded bf16 LDS plane, 448 thr = 16ch x 28w ----------------
#define CT 16
#define PRS 34                    // padded row stride (shorts): 32 cols + 2 skew
#define PCS (32 * PRS + 22)       // channel stride (shorts) = 1110; bank-skews channels
__global__ __launch_bounds__(448) void k_dw(
    __hip_bfloat16* __restrict__ hid, const float* __restrict__ rw,
    const float* __restrict__ dw_w,
    const float* __restrict__ bn2_g, const float* __restrict__ bn2_b,
    const float* __restrict__ bn2_m, const float* __restrict__ bn2_v,
    float* __restrict__ s_out) {
    int ct = blockIdx.x;  // 0..35
    int b = blockIdx.y;
    int tid = threadIdx.x;
    int cb = ct * CT;
    __shared__ unsigned short P[CT * PCS];  // 35.5 KB, zero halo
    __shared__ float kl[CT][25];
    __shared__ float ssum[CT];
    __hip_bfloat16* hb = hid + ((size_t)b * HID + cb) * NPIX;

    // zero-fill P (as uints; CT*PCS = 17760 shorts = 8880 uints)
    for (int i = tid; i < CT * PCS / 2; i += 448) reinterpret_cast<unsigned int*>(P)[i] = 0u;
    if (tid < CT) ssum[tid] = 0.f;
    __syncthreads();
    // interior fill: copy raw bf16 pairs
    const unsigned int* hb32 = reinterpret_cast<const unsigned int*>(hb);
    for (int i = tid; i < CT * (NPIX / 2); i += 448) {
        int ci = i / (NPIX / 2), p2 = i % (NPIX / 2);
        int px = 2 * p2;
        int h = px / WW, w = px % WW;  // w even <= 26, pair stays in-row
        *reinterpret_cast<unsigned int*>(&P[ci * PCS + (h + 2) * PRS + (w + 2)]) = hb32[i];
    }
    // expert-aggregated kernels (BN2 scale folded)
    {
        float rwl[E];
#pragma unroll
        for (int e = 0; e < E; ++e) rwl[e] = rw[b * E + e];
        for (int i = tid; i < CT * 25; i += 448) {
            int ci = i / 25, j = i % 25;
            int c = cb + ci;
            float a = 0.f;
#pragma unroll
            for (int e = 0; e < E; ++e) a += rwl[e] * dw_w[((size_t)e * HID + c) * 25 + j];
            kl[ci][j] = a * (bn2_g[c] * rsqrtf(bn2_v[c] + EPS));
        }
    }
    __syncthreads();

    // one thread per (channel, output column)
    int ci = tid / WW, w = tid % WW;
    const unsigned short* Pc = P + ci * PCS;
    float k[25];
#pragma unroll
    for (int j = 0; j < 25; ++j) k[j] = kl[ci][j];
    int c = cb + ci;
    float inv2 = bn2_g[c] * rsqrtf(bn2_v[c] + EPS);
    float sh2 = bn2_b[c] - bn2_m[c] * inv2;

    float win[5][5];
#pragma unroll
    for (int i = 0; i < 5; ++i)
#pragma unroll
        for (int j = 0; j < 5; ++j) win[i][j] = bf2f(Pc[i * PRS + w + j]);

    float csum = 0.f;
#pragma unroll
    for (int h = 0; h < HH; ++h) {
        float o = 0.f;
#pragma unroll
        for (int i = 0; i < 5; ++i)
#pragma unroll
            for (int j = 0; j < 5; ++j) o += win[i][j] * k[i * 5 + j];
        float t = o + sh2;
        float u = t * sigmoidf_(t);
        csum += u;
        hb[ci * NPIX + h * WW + w] = __float2bfloat16(u);
        if (h < HH - 1) {
#pragma unroll
            for (int i = 0; i < 4; ++i)
#pragma unroll
                for (int j = 0; j < 5; ++j) win[i][j] = win[i + 1][j];
#pragma unroll
            for (int j = 0; j < 5; ++j) win[4][j] = bf2f(Pc[(h + 5) * PRS + w + j]);
        }
    }
    atomicAdd(&ssum[ci], csum);
    __syncthreads();
    if (tid < CT) s_out[(size_t)b * HID + cb + tid] = ssum[tid] * (1.0f / NPIX);
}

// ---------------- K5: SE MLP (recomputed per block) + wpw slice; grid (6, B) ----------------
__global__ __launch_bounds__(256) void k_se_wpw(
    const float* __restrict__ s, const float* __restrict__ se_w1,
    const float* __restrict__ se_b1, const float* __restrict__ se_w2,
    const float* __restrict__ se_b2, const float* __restrict__ rw,
    const float* __restrict__ pw_w,
    const float* __restrict__ bn3_g, const float* __restrict__ bn3_v,
    unsigned short* __restrict__ wpw) {
    int seg = blockIdx.x;  // 0..5 -> oc range
    int b = blockIdx.y;
    int tid = threadIdx.x;
    __shared__ float sl[HID];
    __shared__ float zl[RED];
    __shared__ float scl[HID];
    for (int i = tid; i < HID; i += 256) sl[i] = s[(size_t)b * HID + i];
    __syncthreads();
    if (tid < RED) {
        float a = se_b1[tid];
        for (int c = 0; c < HID; ++c) a += sl[c] * se_w1[tid * HID + c];
        zl[tid] = a * sigmoidf_(a);
    }
    __syncthreads();
    for (int c = tid; c < HID; c += 256) {
        float a = se_b2[c];
#pragma unroll
        for (int r = 0; r < RED; ++r) a += zl[r] * se_w2[c * RED + r];
        scl[c] = sigmoidf_(a);
    }
    __syncthreads();
    float rwl[E];
#pragma unroll
    for (int e = 0; e < E; ++e) rwl[e] = rw[b * E + e];
    unsigned short* wb = wpw + (size_t)b * COUT * HID;
    for (int i = tid; i < 16 * HID; i += 256) {
        int o = seg * 16 + i / HID, c = i % HID;
        float a = 0.f;
#pragma unroll
        for (int e = 0; e < E; ++e) a += rwl[e] * pw_w[((size_t)e * COUT + o) * HID + c];
        float inv3 = bn3_g[o] * rsqrtf(bn3_v[o] + EPS);
        wb[o * HID + c] = f2bf(a * inv3 * scl[c]);
    }
}

// ---------------- K6: pointwise GEMM (MFMA bf16) + BN3 shift + residual -> out ----------------
__global__ __launch_bounds__(448) void k_pw_mfma(
    const __hip_bfloat16* __restrict__ hid, const unsigned short* __restrict__ wpw,  // [b][96][576] bf16
    const float* __restrict__ x,
    const float* __restrict__ bn3_g, const float* __restrict__ bn3_b,
    const float* __restrict__ bn3_m, const float* __restrict__ bn3_v,
    float* __restrict__ out) {
    int nc = blockIdx.x;  // 0..6
    int b = blockIdx.y;
    int tid = threadIdx.x;
    int lane = tid & 63, nf = tid >> 6;
    int col = lane & 15, g = lane >> 4;
    __shared__ unsigned short Wl[96 * 104];  // [m=96][k=96 pad 104]
    __shared__ unsigned short Ht[96 * 116];  // [k=96][px=112 pad 116]
    __shared__ float inv3s[COUT], sh3s[COUT];
    if (tid < COUT) {
        float inv = bn3_g[tid] * rsqrtf(bn3_v[tid] + EPS);
        inv3s[tid] = inv;
        sh3s[tid] = bn3_b[tid] - bn3_m[tid] * inv;
    }
    const unsigned short* hb = (const unsigned short*)hid + (size_t)b * HID * NPIX + nc * 112;
    const unsigned short* wb = wpw + (size_t)b * COUT * HID;
    f32x4 acc[6];
#pragma unroll
    for (int m = 0; m < 6; ++m) acc[m] = (f32x4){0.f, 0.f, 0.f, 0.f};

    for (int ks = 0; ks < 6; ++ks) {
        __syncthreads();
        for (int i = tid; i < 96 * 48; i += 448) {
            int m = i / 48, k2 = i % 48;
            *(uint*)&Wl[m * 104 + 2 * k2] = *(const uint*)&wb[m * HID + ks * 96 + 2 * k2];
        }
        for (int i = tid; i < 96 * 56; i += 448) {
            int k = i / 56, p2 = i % 56;
            *(uint*)&Ht[k * 116 + 2 * p2] = *(const uint*)&hb[((size_t)(ks * 96 + k)) * NPIX + 2 * p2];
        }
        __syncthreads();
#pragma unroll
        for (int kk = 0; kk < 3; ++kk) {
            int k0 = kk * 32 + 8 * g;
            short8v bfr;
#pragma unroll
            for (int j = 0; j < 8; ++j) bfr[j] = (short)Ht[(k0 + j) * 116 + nf * 16 + col];
#pragma unroll
            for (int m = 0; m < 6; ++m) {
                short8v af = *(const short8v*)&Wl[(m * 16 + col) * 104 + kk * 32 + 8 * g];
                acc[m] = __builtin_amdgcn_mfma_f32_16x16x32_bf16(af, bfr, acc[m], 0, 0, 0);
            }
        }
    }
    int px = nc * 112 + nf * 16 + col;
#pragma unroll
    for (int m = 0; m < 6; ++m) {
#pragma unroll
        for (int r = 0; r < 4; ++r) {
            int oc = m * 16 + 4 * g + r;
            size_t off = ((size_t)b * COUT + oc) * NPIX + px;
            out[off] = acc[m][r] + sh3s[oc] + x[off];
        }
    }
}

extern "C" void kernel_launch(void* const* d_in, const int* in_sizes, int n_in,
                              void* d_out, int out_size, void* d_ws, size_t ws_size,
                              hipStream_t stream) {
    const float* x     = (const float*)d_in[0];
    const float* r_w1  = (const float*)d_in[1];
    const float* r_b1  = (const float*)d_in[2];
    const float* r_w2  = (const float*)d_in[3];
    const float* r_b2  = (const float*)d_in[4];
    const float* exp_w = (const float*)d_in[5];
    const float* bn1_g = (const float*)d_in[6];
    const float* bn1_b = (const float*)d_in[7];
    const float* bn1_m = (const float*)d_in[8];
    const float* bn1_v = (const float*)d_in[9];
    const float* dw_w  = (const float*)d_in[10];
    const float* bn2_g = (const float*)d_in[11];
    const float* bn2_b = (const float*)d_in[12];
    const float* bn2_m = (const float*)d_in[13];
    const float* bn2_v = (const float*)d_in[14];
    const float* se_w1 = (const float*)d_in[15];
    const float* se_b1 = (const float*)d_in[16];
    const float* se_w2 = (const float*)d_in[17];
    const float* se_b2 = (const float*)d_in[18];
    const float* pw_w  = (const float*)d_in[19];
    const float* bn3_g = (const float*)d_in[20];
    const float* bn3_b = (const float*)d_in[21];
    const float* bn3_m = (const float*)d_in[22];
    const float* bn3_v = (const float*)d_in[23];
    float* out = (float*)d_out;

    char* ws = (char*)d_ws;
    float* rw                 = (float*)(ws + 0);        // 1 KB
    float* pool               = (float*)(ws + 1024);     // 24 KB
    float* s                  = (float*)(ws + 26624);    // 147 KB
    unsigned short* exp_w_bf  = (unsigned short*)(ws + 174336);   // 110 KB
    unsigned short* wpw_bf    = (unsigned short*)(ws + 285184);   // 7.08 MB
    __hip_bfloat16* hid       = (__hip_bfloat16*)(ws + 7363328);  // 57.8 MB

    k_pool<<<B * CIN / 4, 256, 0, stream>>>(x, pool);
    k_mlp<<<1, 256, 0, stream>>>(pool, r_w1, r_b1, r_w2, r_b2, rw);
    k_wcvt<<<(HID * CIN + 255) / 256, 256, 0, stream>>>(exp_w, exp_w_bf);
    k_expand_mfma<<<dim3(7, B), 256, 0, stream>>>(x, exp_w_bf, bn1_g, bn1_b, bn1_m, bn1_v, hid);
    k_dw<<<dim3(36, B), 448, 0, stream>>>(hid, rw, dw_w, bn2_g, bn2_b, bn2_m, bn2_v, s);
    k_se_wpw<<<dim3(6, B), 256, 0, stream>>>(s, se_w1, se_b1, se_w2, se_b2, rw, pw_w, bn3_g, bn3_v, wpw_bf);
    k_pw_mfma<<<dim3(7, B), 448, 0, stream>>>(hid, wpw_bf, x, bn3_g, bn3_b, bn3_m, bn3_v, out);
}

// Round 6
// 324.682 us; speedup vs baseline: 1.1135x; 1.1135x over previous
//
#include <hip/hip_runtime.h>
#include <hip/hip_bf16.h>
#include <math.h>

#define B 64
#define CIN 96
#define HH 28
#define WW 28
#define NPIX 784
#define E 4
#define HID 576
#define RED 24
#define RHID 24
#define COUT 96
#define EPS 1e-3f

typedef __attribute__((ext_vector_type(8))) short short8v;
typedef __attribute__((ext_vector_type(4))) float f32x4;

__device__ __forceinline__ float sigmoidf_(float v) { return 1.0f / (1.0f + __expf(-v)); }

__device__ __forceinline__ unsigned short f2bf(float v) {
    __hip_bfloat16 h = __float2bfloat16(v);
    return *reinterpret_cast<unsigned short*>(&h);
}

__device__ __forceinline__ float bf2f(unsigned short u) {
    unsigned int w = ((unsigned int)u) << 16;
    return *reinterpret_cast<float*>(&w);
}

// ---------------- K1a: pool[b][c] = mean over pixels; one wave per (b,c) row ----------------
__global__ __launch_bounds__(256) void k_pool(const float* __restrict__ x, float* __restrict__ pool) {
    int row = blockIdx.x * 4 + (threadIdx.x >> 6);  // b*CIN + c  (0..6143)
    int lane = threadIdx.x & 63;
    const float4* xr = reinterpret_cast<const float4*>(x + (size_t)row * NPIX);  // 196 float4
    float s = 0.f;
    for (int i = lane; i < 196; i += 64) {
        float4 v = xr[i];
        s += v.x + v.y + v.z + v.w;
    }
#pragma unroll
    for (int off = 32; off > 0; off >>= 1) s += __shfl_down(s, off);
    if (lane == 0) pool[row] = s * (1.0f / NPIX);
}

// ---------------- K1b: MLP + softmax for all samples; 1 block, thread t = sample t ----------------
__global__ __launch_bounds__(256) void k_mlp(const float* __restrict__ pool,
                                             const float* __restrict__ r_w1, const float* __restrict__ r_b1,
                                             const float* __restrict__ r_w2, const float* __restrict__ r_b2,
                                             float* __restrict__ rw) {
    __shared__ float w1[RHID * CIN];
    __shared__ float b1s[RHID];
    __shared__ float w2[E * RHID];
    __shared__ float b2s[E];
    __shared__ float pl[B * CIN];
    int tid = threadIdx.x;
    for (int i = tid; i < RHID * CIN; i += 256) w1[i] = r_w1[i];
    if (tid < RHID) b1s[tid] = r_b1[tid];
    if (tid < E * RHID) w2[tid] = r_w2[tid];
    if (tid < E) b2s[tid] = r_b2[tid];
    for (int i = tid; i < B * CIN; i += 256) pl[i] = pool[i];
    __syncthreads();
    if (tid < B) {
        const float* p = pl + tid * CIN;
        float hdn[RHID];
#pragma unroll
        for (int r = 0; r < RHID; ++r) {
            float a = b1s[r];
            for (int c = 0; c < CIN; ++c) a += p[c] * w1[r * CIN + c];
            hdn[r] = fmaxf(a, 0.f);
        }
        float lg[E];
        float mx = -1e30f;
#pragma unroll
        for (int e = 0; e < E; ++e) {
            float a = b2s[e];
#pragma unroll
            for (int r = 0; r < RHID; ++r) a += hdn[r] * w2[e * RHID + r];
            lg[e] = a;
            mx = fmaxf(mx, a);
        }
        float den = 0.f;
#pragma unroll
        for (int e = 0; e < E; ++e) { lg[e] = __expf(lg[e] - mx); den += lg[e]; }
#pragma unroll
        for (int e = 0; e < E; ++e) rw[tid * E + e] = lg[e] / den;
    }
}

// ---------------- K2b: exp_w -> bf16 ----------------
__global__ void k_wcvt(const float* __restrict__ w, unsigned short* __restrict__ wb) {
    int i = blockIdx.x * blockDim.x + threadIdx.x;
    if (i < HID * CIN) wb[i] = f2bf(w[i]);
}

// ---------------- K3: expand GEMM (MFMA bf16) + BN1 + SiLU -> hid (bf16 [b][c][p]) ----------------
__global__ __launch_bounds__(256) void k_expand_mfma(
    const float* __restrict__ x, const unsigned short* __restrict__ w_bf,  // [576][96] bf16
    const float* __restrict__ bn1_g, const float* __restrict__ bn1_b,
    const float* __restrict__ bn1_m, const float* __restrict__ bn1_v,
    __hip_bfloat16* __restrict__ hid) {
    int nc = blockIdx.x;  // 0..6
    int b = blockIdx.y;
    int tid = threadIdx.x;
    int lane = tid & 63, wv = tid >> 6;
    int col = lane & 15, g = lane >> 4;
    __shared__ unsigned short xt[96 * 116];  // [k=96][px=112 pad 116] bf16
    __shared__ float inv1s[HID], sh1s[HID];

    for (int i = tid; i < HID; i += 256) {
        float inv = bn1_g[i] * rsqrtf(bn1_v[i] + EPS);
        inv1s[i] = inv;
        sh1s[i] = bn1_b[i] - bn1_m[i] * inv;
    }
    const float* xb = x + (size_t)b * CIN * NPIX + nc * 112;
    for (int i = tid; i < 96 * 28; i += 256) {
        int c = i / 28, q = i % 28;
        float4 v = *reinterpret_cast<const float4*>(&xb[c * NPIX + q * 4]);
        ushort4 s;
        s.x = f2bf(v.x); s.y = f2bf(v.y); s.z = f2bf(v.z); s.w = f2bf(v.w);
        *reinterpret_cast<ushort4*>(&xt[c * 116 + q * 4]) = s;
    }
    __syncthreads();

    const short8v* wv8 = reinterpret_cast<const short8v*>(w_bf);
    for (int nf = 0; nf < 7; ++nf) {
        int pcol = nf * 16 + col;
        short8v bfr[3];
#pragma unroll
        for (int kk = 0; kk < 3; ++kk) {
            int k0 = kk * 32 + 8 * g;
#pragma unroll
            for (int j = 0; j < 8; ++j) bfr[kk][j] = (short)xt[(k0 + j) * 116 + pcol];
        }
        int px = nc * 112 + pcol;
#pragma unroll
        for (int mi = 0; mi < 9; ++mi) {
            int mb = (wv * 9 + mi) * 16;
            f32x4 acc = {0.f, 0.f, 0.f, 0.f};
#pragma unroll
            for (int kk = 0; kk < 3; ++kk) {
                short8v af = wv8[((mb + col) * 96 + kk * 32 + 8 * g) >> 3];
                acc = __builtin_amdgcn_mfma_f32_16x16x32_bf16(af, bfr[kk], acc, 0, 0, 0);
            }
#pragma unroll
            for (int r = 0; r < 4; ++r) {
                int oc = mb + 4 * g + r;
                float t = acc[r] * inv1s[oc] + sh1s[oc];
                float u = t * sigmoidf_(t);
                hid[((size_t)b * HID + oc) * NPIX + px] = __float2bfloat16(u);
            }
        }
    }
}

// ---------------- K4: depthwise 5x5, fp32 zero-halo LDS plane, 448 thr = 16ch x 28cols ----------------
// r3 numerics (fp32 taps, fp32 kernel, scalar fmac) + r4's verified halo geometry, no converts on read path.
#define CT 16
#define RSF 33                 // padded row stride (floats): 32 used cols + 1 skew
#define PCSF 1063              // channel stride (floats) = 32*33 + 7; 1063 % 32 = 7 -> bank rotation
__global__ __launch_bounds__(448) void k_dw(
    __hip_bfloat16* __restrict__ hid, const float* __restrict__ rw,
    const float* __restrict__ dw_w,
    const float* __restrict__ bn2_g, const float* __restrict__ bn2_b,
    const float* __restrict__ bn2_m, const float* __restrict__ bn2_v,
    float* __restrict__ s_out) {
    int ct = blockIdx.x;  // 0..35
    int b = blockIdx.y;
    int tid = threadIdx.x;
    int cb = ct * CT;
    __shared__ float PF[CT * PCSF];  // 68 KB, zero halo
    __shared__ float kl[CT][25];
    __shared__ float ssum[CT];
    __hip_bfloat16* hb = hid + ((size_t)b * HID + cb) * NPIX;

    // phase 0: zero plane (halo)
    for (int i = tid; i < CT * PCSF; i += 448) PF[i] = 0.f;
    if (tid < CT) ssum[tid] = 0.f;
    __syncthreads();

    // phase 1: interior fill (one image row per thread; bf16 -> f32 once per pixel) + kernel agg
    int ci = tid / 28, w = tid - ci * 28;  // (channel-in-tile, image row) for fill; (channel, out col) for conv
    {
        const unsigned int* src = reinterpret_cast<const unsigned int*>(hb) + ci * (NPIX / 2) + w * 14;
        float* dst = PF + ci * PCSF + (w + 2) * RSF + 2;
#pragma unroll
        for (int d = 0; d < 14; ++d) {
            unsigned int v = src[d];
            dst[2 * d]     = bf2f((unsigned short)(v & 0xffffu));
            dst[2 * d + 1] = bf2f((unsigned short)(v >> 16));
        }
    }
    {
        float rwl[E];
#pragma unroll
        for (int e = 0; e < E; ++e) rwl[e] = rw[b * E + e];
        for (int i = tid; i < CT * 25; i += 448) {
            int c2 = i / 25, j = i % 25;
            int c = cb + c2;
            float a = 0.f;
#pragma unroll
            for (int e = 0; e < E; ++e) a += rwl[e] * dw_w[((size_t)e * HID + c) * 25 + j];
            kl[c2][j] = a * (bn2_g[c] * rsqrtf(bn2_v[c] + EPS));
        }
    }
    __syncthreads();

    // phase 2: conv; taps at plane cols w..w+4 (image cols w-2..w+2), rows h..h+4
    const float* Pc = PF + ci * PCSF + w;
    float k[25];
#pragma unroll
    for (int j = 0; j < 25; ++j) k[j] = kl[ci][j];
    int c = cb + ci;
    float inv2 = bn2_g[c] * rsqrtf(bn2_v[c] + EPS);
    float sh2 = bn2_b[c] - bn2_m[c] * inv2;
    unsigned short* hout = reinterpret_cast<unsigned short*>(hb) + ci * NPIX + w;

    float win[5][5];
#pragma unroll
    for (int i = 0; i < 5; ++i)
#pragma unroll
        for (int j = 0; j < 5; ++j) win[i][j] = Pc[i * RSF + j];

    float csum = 0.f;
#pragma unroll
    for (int h = 0; h < HH; ++h) {
        float o = 0.f;
#pragma unroll
        for (int i = 0; i < 5; ++i)
#pragma unroll
            for (int j = 0; j < 5; ++j) o += win[i][j] * k[i * 5 + j];
        float t = o + sh2;
        float u = t * sigmoidf_(t);
        csum += u;
        hout[h * WW] = f2bf(u);
        if (h < HH - 1) {
#pragma unroll
            for (int i = 0; i < 4; ++i)
#pragma unroll
                for (int j = 0; j < 5; ++j) win[i][j] = win[i + 1][j];
#pragma unroll
            for (int j = 0; j < 5; ++j) win[4][j] = Pc[(h + 5) * RSF + j];
        }
    }
    atomicAdd(&ssum[ci], csum);
    __syncthreads();
    if (tid < CT) s_out[(size_t)b * HID + cb + tid] = ssum[tid] * (1.0f / NPIX);
}

// ---------------- K5: SE MLP (recomputed per block) + wpw slice; grid (6, B) ----------------
__global__ __launch_bounds__(256) void k_se_wpw(
    const float* __restrict__ s, const float* __restrict__ se_w1,
    const float* __restrict__ se_b1, const float* __restrict__ se_w2,
    const float* __restrict__ se_b2, const float* __restrict__ rw,
    const float* __restrict__ pw_w,
    const float* __restrict__ bn3_g, const float* __restrict__ bn3_v,
    unsigned short* __restrict__ wpw) {
    int seg = blockIdx.x;  // 0..5 -> oc range
    int b = blockIdx.y;
    int tid = threadIdx.x;
    __shared__ float sl[HID];
    __shared__ float zl[RED];
    __shared__ float scl[HID];
    for (int i = tid; i < HID; i += 256) sl[i] = s[(size_t)b * HID + i];
    __syncthreads();
    if (tid < RED) {
        float a = se_b1[tid];
        for (int c = 0; c < HID; ++c) a += sl[c] * se_w1[tid * HID + c];
        zl[tid] = a * sigmoidf_(a);
    }
    __syncthreads();
    for (int c = tid; c < HID; c += 256) {
        float a = se_b2[c];
#pragma unroll
        for (int r = 0; r < RED; ++r) a += zl[r] * se_w2[c * RED + r];
        scl[c] = sigmoidf_(a);
    }
    __syncthreads();
    float rwl[E];
#pragma unroll
    for (int e = 0; e < E; ++e) rwl[e] = rw[b * E + e];
    unsigned short* wb = wpw + (size_t)b * COUT * HID;
    for (int i = tid; i < 16 * HID; i += 256) {
        int o = seg * 16 + i / HID, c = i % HID;
        float a = 0.f;
#pragma unroll
        for (int e = 0; e < E; ++e) a += rwl[e] * pw_w[((size_t)e * COUT + o) * HID + c];
        float inv3 = bn3_g[o] * rsqrtf(bn3_v[o] + EPS);
        wb[o * HID + c] = f2bf(a * inv3 * scl[c]);
    }
}

// ---------------- K6: pointwise GEMM (MFMA bf16) + BN3 shift + residual -> out ----------------
__global__ __launch_bounds__(448) void k_pw_mfma(
    const __hip_bfloat16* __restrict__ hid, const unsigned short* __restrict__ wpw,  // [b][96][576] bf16
    const float* __restrict__ x,
    const float* __restrict__ bn3_g, const float* __restrict__ bn3_b,
    const float* __restrict__ bn3_m, const float* __restrict__ bn3_v,
    float* __restrict__ out) {
    int nc = blockIdx.x;  // 0..6
    int b = blockIdx.y;
    int tid = threadIdx.x;
    int lane = tid & 63, nf = tid >> 6;
    int col = lane & 15, g = lane >> 4;
    __shared__ unsigned short Wl[96 * 104];  // [m=96][k=96 pad 104]
    __shared__ unsigned short Ht[96 * 116];  // [k=96][px=112 pad 116]
    __shared__ float inv3s[COUT], sh3s[COUT];
    if (tid < COUT) {
        float inv = bn3_g[tid] * rsqrtf(bn3_v[tid] + EPS);
        inv3s[tid] = inv;
        sh3s[tid] = bn3_b[tid] - bn3_m[tid] * inv;
    }
    const unsigned short* hb = (const unsigned short*)hid + (size_t)b * HID * NPIX + nc * 112;
    const unsigned short* wb = wpw + (size_t)b * COUT * HID;
    f32x4 acc[6];
#pragma unroll
    for (int m = 0; m < 6; ++m) acc[m] = (f32x4){0.f, 0.f, 0.f, 0.f};

    for (int ks = 0; ks < 6; ++ks) {
        __syncthreads();
        for (int i = tid; i < 96 * 48; i += 448) {
            int m = i / 48, k2 = i % 48;
            *(uint*)&Wl[m * 104 + 2 * k2] = *(const uint*)&wb[m * HID + ks * 96 + 2 * k2];
        }
        for (int i = tid; i < 96 * 56; i += 448) {
            int k = i / 56, p2 = i % 56;
            *(uint*)&Ht[k * 116 + 2 * p2] = *(const uint*)&hb[((size_t)(ks * 96 + k)) * NPIX + 2 * p2];
        }
        __syncthreads();
#pragma unroll
        for (int kk = 0; kk < 3; ++kk) {
            int k0 = kk * 32 + 8 * g;
            short8v bfr;
#pragma unroll
            for (int j = 0; j < 8; ++j) bfr[j] = (short)Ht[(k0 + j) * 116 + nf * 16 + col];
#pragma unroll
            for (int m = 0; m < 6; ++m) {
                short8v af = *(const short8v*)&Wl[(m * 16 + col) * 104 + kk * 32 + 8 * g];
                acc[m] = __builtin_amdgcn_mfma_f32_16x16x32_bf16(af, bfr, acc[m], 0, 0, 0);
            }
        }
    }
    int px = nc * 112 + nf * 16 + col;
#pragma unroll
    for (int m = 0; m < 6; ++m) {
#pragma unroll
        for (int r = 0; r < 4; ++r) {
            int oc = m * 16 + 4 * g + r;
            size_t off = ((size_t)b * COUT + oc) * NPIX + px;
            out[off] = acc[m][r] + sh3s[oc] + x[off];
        }
    }
}

extern "C" void kernel_launch(void* const* d_in, const int* in_sizes, int n_in,
                              void* d_out, int out_size, void* d_ws, size_t ws_size,
                              hipStream_t stream) {
    const float* x     = (const float*)d_in[0];
    const float* r_w1  = (const float*)d_in[1];
    const float* r_b1  = (const float*)d_in[2];
    const float* r_w2  = (const float*)d_in[3];
    const float* r_b2  = (const float*)d_in[4];
    const float* exp_w = (const float*)d_in[5];
    const float* bn1_g = (const float*)d_in[6];
    const float* bn1_b = (const float*)d_in[7];
    const float* bn1_m = (const float*)d_in[8];
    const float* bn1_v = (const float*)d_in[9];
    const float* dw_w  = (const float*)d_in[10];
    const float* bn2_g = (const float*)d_in[11];
    const float* bn2_b = (const float*)d_in[12];
    const float* bn2_m = (const float*)d_in[13];
    const float* bn2_v = (const float*)d_in[14];
    const float* se_w1 = (const float*)d_in[15];
    const float* se_b1 = (const float*)d_in[16];
    const float* se_w2 = (const float*)d_in[17];
    const float* se_b2 = (const float*)d_in[18];
    const float* pw_w  = (const float*)d_in[19];
    const float* bn3_g = (const float*)d_in[20];
    const float* bn3_b = (const float*)d_in[21];
    const float* bn3_m = (const float*)d_in[22];
    const float* bn3_v = (const float*)d_in[23];
    float* out = (float*)d_out;

    char* ws = (char*)d_ws;
    float* rw                 = (float*)(ws + 0);        // 1 KB
    float* pool               = (float*)(ws + 1024);     // 24 KB
    float* s                  = (float*)(ws + 26624);    // 147 KB
    unsigned short* exp_w_bf  = (unsigned short*)(ws + 174336);   // 110 KB
    unsigned short* wpw_bf    = (unsigned short*)(ws + 285184);   // 7.08 MB
    __hip_bfloat16* hid       = (__hip_bfloat16*)(ws + 7363328);  // 57.8 MB

    k_pool<<<B * CIN / 4, 256, 0, stream>>>(x, pool);
    k_mlp<<<1, 256, 0, stream>>>(pool, r_w1, r_b1, r_w2, r_b2, rw);
    k_wcvt<<<(HID * CIN + 255) / 256, 256, 0, stream>>>(exp_w, exp_w_bf);
    k_expand_mfma<<<dim3(7, B), 256, 0, stream>>>(x, exp_w_bf, bn1_g, bn1_b, bn1_m, bn1_v, hid);
    k_dw<<<dim3(36, B), 448, 0, stream>>>(hid, rw, dw_w, bn2_g, bn2_b, bn2_m, bn2_v, s);
    k_se_wpw<<<dim3(6, B), 256, 0, stream>>>(s, se_w1, se_b1, se_w2, se_b2, rw, pw_w, bn3_g, bn3_v, wpw_bf);
    k_pw_mfma<<<dim3(7, B), 448, 0, stream>>>(hid, wpw_bf, x, bn3_g, bn3_b, bn3_m, bn3_v, out);
}

// Round 7
// 295.873 us; speedup vs baseline: 1.2219x; 1.0974x over previous
//
#include <hip/hip_runtime.h>
#include <hip/hip_bf16.h>
#include <math.h>

#define B 64
#define CIN 96
#define HH 28
#define WW 28
#define NPIX 784
#define E 4
#define HID 576
#define RED 24
#define RHID 24
#define COUT 96
#define EPS 1e-3f

typedef __attribute__((ext_vector_type(8))) short short8v;
typedef __attribute__((ext_vector_type(4))) float f32x4;

__device__ __forceinline__ float sigmoidf_(float v) { return 1.0f / (1.0f + __expf(-v)); }

__device__ __forceinline__ unsigned short f2bf(float v) {
    __hip_bfloat16 h = __float2bfloat16(v);
    return *reinterpret_cast<unsigned short*>(&h);
}

__device__ __forceinline__ float bf2f(unsigned short u) {
    unsigned int w = ((unsigned int)u) << 16;
    return *reinterpret_cast<float*>(&w);
}

// ---------------- K1a: pool[b][c] = mean over pixels (blocks 0..1535); exp_w->bf16 (blocks 1536..1751) ----------------
__global__ __launch_bounds__(256) void k_pool_wcvt(const float* __restrict__ x, float* __restrict__ pool,
                                                   const float* __restrict__ w, unsigned short* __restrict__ wb) {
    if (blockIdx.x < 1536) {
        int row = blockIdx.x * 4 + (threadIdx.x >> 6);  // b*CIN + c  (0..6143)
        int lane = threadIdx.x & 63;
        const float4* xr = reinterpret_cast<const float4*>(x + (size_t)row * NPIX);  // 196 float4
        float s = 0.f;
        for (int i = lane; i < 196; i += 64) {
            float4 v = xr[i];
            s += v.x + v.y + v.z + v.w;
        }
#pragma unroll
        for (int off = 32; off > 0; off >>= 1) s += __shfl_down(s, off);
        if (lane == 0) pool[row] = s * (1.0f / NPIX);
    } else {
        int i = (blockIdx.x - 1536) * 256 + threadIdx.x;  // 216*256 == HID*CIN exactly
        wb[i] = f2bf(w[i]);
    }
}

// ---------------- K1b: MLP + softmax for all samples; 1 block, thread t = sample t ----------------
__global__ __launch_bounds__(256) void k_mlp(const float* __restrict__ pool,
                                             const float* __restrict__ r_w1, const float* __restrict__ r_b1,
                                             const float* __restrict__ r_w2, const float* __restrict__ r_b2,
                                             float* __restrict__ rw) {
    __shared__ float w1[RHID * CIN];
    __shared__ float b1s[RHID];
    __shared__ float w2[E * RHID];
    __shared__ float b2s[E];
    __shared__ float pl[B * CIN];
    int tid = threadIdx.x;
    for (int i = tid; i < RHID * CIN; i += 256) w1[i] = r_w1[i];
    if (tid < RHID) b1s[tid] = r_b1[tid];
    if (tid < E * RHID) w2[tid] = r_w2[tid];
    if (tid < E) b2s[tid] = r_b2[tid];
    for (int i = tid; i < B * CIN; i += 256) pl[i] = pool[i];
    __syncthreads();
    if (tid < B) {
        const float* p = pl + tid * CIN;
        float hdn[RHID];
#pragma unroll
        for (int r = 0; r < RHID; ++r) {
            float a = b1s[r];
            for (int c = 0; c < CIN; ++c) a += p[c] * w1[r * CIN + c];
            hdn[r] = fmaxf(a, 0.f);
        }
        float lg[E];
        float mx = -1e30f;
#pragma unroll
        for (int e = 0; e < E; ++e) {
            float a = b2s[e];
#pragma unroll
            for (int r = 0; r < RHID; ++r) a += hdn[r] * w2[e * RHID + r];
            lg[e] = a;
            mx = fmaxf(mx, a);
        }
        float den = 0.f;
#pragma unroll
        for (int e = 0; e < E; ++e) { lg[e] = __expf(lg[e] - mx); den += lg[e]; }
#pragma unroll
        for (int e = 0; e < E; ++e) rw[tid * E + e] = lg[e] / den;
    }
}

// ---------------- K3: expand GEMM (MFMA bf16) + BN1 + SiLU -> hid (bf16 [b][c][p]) ----------------
// af (A-fragments) hoisted to registers: 27 global b128 gathers per wave, reused across all 7 nf.
__global__ __launch_bounds__(256) void k_expand_mfma(
    const float* __restrict__ x, const unsigned short* __restrict__ w_bf,  // [576][96] bf16
    const float* __restrict__ bn1_g, const float* __restrict__ bn1_b,
    const float* __restrict__ bn1_m, const float* __restrict__ bn1_v,
    __hip_bfloat16* __restrict__ hid) {
    int nc = blockIdx.x;  // 0..6
    int b = blockIdx.y;
    int tid = threadIdx.x;
    int lane = tid & 63, wv = tid >> 6;
    int col = lane & 15, g = lane >> 4;
    __shared__ unsigned short xt[96 * 116];  // [k=96][px=112 pad 116] bf16
    __shared__ float inv1s[HID], sh1s[HID];

    for (int i = tid; i < HID; i += 256) {
        float inv = bn1_g[i] * rsqrtf(bn1_v[i] + EPS);
        inv1s[i] = inv;
        sh1s[i] = bn1_b[i] - bn1_m[i] * inv;
    }
    const float* xb = x + (size_t)b * CIN * NPIX + nc * 112;
    for (int i = tid; i < 96 * 28; i += 256) {
        int c = i / 28, q = i % 28;
        float4 v = *reinterpret_cast<const float4*>(&xb[c * NPIX + q * 4]);
        ushort4 s;
        s.x = f2bf(v.x); s.y = f2bf(v.y); s.z = f2bf(v.z); s.w = f2bf(v.w);
        *reinterpret_cast<ushort4*>(&xt[c * 116 + q * 4]) = s;
    }

    // hoist A-fragments (weights) into registers while staging settles
    const short8v* wv8 = reinterpret_cast<const short8v*>(w_bf);
    short8v af[9][3];
#pragma unroll
    for (int mi = 0; mi < 9; ++mi) {
#pragma unroll
        for (int kk = 0; kk < 3; ++kk)
            af[mi][kk] = wv8[(((wv * 9 + mi) * 16 + col) * 96 + kk * 32 + 8 * g) >> 3];
    }
    __syncthreads();

    for (int nf = 0; nf < 7; ++nf) {
        int pcol = nf * 16 + col;
        short8v bfr[3];
#pragma unroll
        for (int kk = 0; kk < 3; ++kk) {
            int k0 = kk * 32 + 8 * g;
#pragma unroll
            for (int j = 0; j < 8; ++j) bfr[kk][j] = (short)xt[(k0 + j) * 116 + pcol];
        }
        int px = nc * 112 + pcol;
#pragma unroll
        for (int mi = 0; mi < 9; ++mi) {
            int mb = (wv * 9 + mi) * 16;
            f32x4 acc = {0.f, 0.f, 0.f, 0.f};
#pragma unroll
            for (int kk = 0; kk < 3; ++kk)
                acc = __builtin_amdgcn_mfma_f32_16x16x32_bf16(af[mi][kk], bfr[kk], acc, 0, 0, 0);
#pragma unroll
            for (int r = 0; r < 4; ++r) {
                int oc = mb + 4 * g + r;
                float t = acc[r] * inv1s[oc] + sh1s[oc];
                float u = t * sigmoidf_(t);
                hid[((size_t)b * HID + oc) * NPIX + px] = __float2bfloat16(u);
            }
        }
    }
}

// ---------------- K4: depthwise 5x5, fp32 zero-halo LDS plane, 448 thr = 16ch x 28cols ----------------
#define CT 16
#define RSF 33                 // padded row stride (floats)
#define PCSF 1063              // channel stride (floats); 1063 % 32 = 7 -> bank rotation
__global__ __launch_bounds__(448) void k_dw(
    __hip_bfloat16* __restrict__ hid, const float* __restrict__ rw,
    const float* __restrict__ dw_w,
    const float* __restrict__ bn2_g, const float* __restrict__ bn2_b,
    const float* __restrict__ bn2_m, const float* __restrict__ bn2_v,
    float* __restrict__ s_out) {
    int ct = blockIdx.x;  // 0..35
    int b = blockIdx.y;
    int tid = threadIdx.x;
    int cb = ct * CT;
    __shared__ float PF[CT * PCSF];  // 68 KB, zero halo
    __shared__ float kl[CT][25];
    __shared__ float ssum[CT];
    __hip_bfloat16* hb = hid + ((size_t)b * HID + cb) * NPIX;

    for (int i = tid; i < CT * PCSF; i += 448) PF[i] = 0.f;
    if (tid < CT) ssum[tid] = 0.f;
    __syncthreads();

    int ci = tid / 28, w = tid - ci * 28;
    {
        const unsigned int* src = reinterpret_cast<const unsigned int*>(hb) + ci * (NPIX / 2) + w * 14;
        float* dst = PF + ci * PCSF + (w + 2) * RSF + 2;
#pragma unroll
        for (int d = 0; d < 14; ++d) {
            unsigned int v = src[d];
            dst[2 * d]     = bf2f((unsigned short)(v & 0xffffu));
            dst[2 * d + 1] = bf2f((unsigned short)(v >> 16));
        }
    }
    {
        float rwl[E];
#pragma unroll
        for (int e = 0; e < E; ++e) rwl[e] = rw[b * E + e];
        for (int i = tid; i < CT * 25; i += 448) {
            int c2 = i / 25, j = i % 25;
            int c = cb + c2;
            float a = 0.f;
#pragma unroll
            for (int e = 0; e < E; ++e) a += rwl[e] * dw_w[((size_t)e * HID + c) * 25 + j];
            kl[c2][j] = a * (bn2_g[c] * rsqrtf(bn2_v[c] + EPS));
        }
    }
    __syncthreads();

    const float* Pc = PF + ci * PCSF + w;
    float k[25];
#pragma unroll
    for (int j = 0; j < 25; ++j) k[j] = kl[ci][j];
    int c = cb + ci;
    float inv2 = bn2_g[c] * rsqrtf(bn2_v[c] + EPS);
    float sh2 = bn2_b[c] - bn2_m[c] * inv2;
    unsigned short* hout = reinterpret_cast<unsigned short*>(hb) + ci * NPIX + w;

    float win[5][5];
#pragma unroll
    for (int i = 0; i < 5; ++i)
#pragma unroll
        for (int j = 0; j < 5; ++j) win[i][j] = Pc[i * RSF + j];

    float csum = 0.f;
#pragma unroll
    for (int h = 0; h < HH; ++h) {
        float o = 0.f;
#pragma unroll
        for (int i = 0; i < 5; ++i)
#pragma unroll
            for (int j = 0; j < 5; ++j) o += win[i][j] * k[i * 5 + j];
        float t = o + sh2;
        float u = t * sigmoidf_(t);
        csum += u;
        hout[h * WW] = f2bf(u);
        if (h < HH - 1) {
#pragma unroll
            for (int i = 0; i < 4; ++i)
#pragma unroll
                for (int j = 0; j < 5; ++j) win[i][j] = win[i + 1][j];
#pragma unroll
            for (int j = 0; j < 5; ++j) win[4][j] = Pc[(h + 5) * RSF + j];
        }
    }
    atomicAdd(&ssum[ci], csum);
    __syncthreads();
    if (tid < CT) s_out[(size_t)b * HID + cb + tid] = ssum[tid] * (1.0f / NPIX);
}

// ---------------- K5: SE MLP (parallel dot) + wpw slice; grid (6, B) ----------------
__global__ __launch_bounds__(256) void k_se_wpw(
    const float* __restrict__ s, const float* __restrict__ se_w1,
    const float* __restrict__ se_b1, const float* __restrict__ se_w2,
    const float* __restrict__ se_b2, const float* __restrict__ rw,
    const float* __restrict__ pw_w,
    const float* __restrict__ bn3_g, const float* __restrict__ bn3_v,
    unsigned short* __restrict__ wpw) {
    int seg = blockIdx.x;  // 0..5 -> oc range
    int b = blockIdx.y;
    int tid = threadIdx.x;
    __shared__ float sl[HID];
    __shared__ float zl[RED];
    __shared__ float scl[HID];
    for (int i = tid; i < HID; i += 256) sl[i] = s[(size_t)b * HID + i];
    __syncthreads();
    if (tid < RED * 8) {  // 192 threads: output r = tid/8, 8-lane strided dot + shuffle tree
        int r = tid >> 3, l = tid & 7;
        float a = 0.f;
        for (int c = l; c < HID; c += 8) a += sl[c] * se_w1[r * HID + c];
        a += __shfl_down(a, 4, 8);
        a += __shfl_down(a, 2, 8);
        a += __shfl_down(a, 1, 8);
        if (l == 0) {
            a += se_b1[r];
            zl[r] = a * sigmoidf_(a);
        }
    }
    __syncthreads();
    for (int c = tid; c < HID; c += 256) {
        float a = se_b2[c];
#pragma unroll
        for (int r = 0; r < RED; ++r) a += zl[r] * se_w2[c * RED + r];
        scl[c] = sigmoidf_(a);
    }
    __syncthreads();
    float rwl[E];
#pragma unroll
    for (int e = 0; e < E; ++e) rwl[e] = rw[b * E + e];
    unsigned short* wb = wpw + (size_t)b * COUT * HID;
    for (int i = tid; i < 16 * HID; i += 256) {
        int o = seg * 16 + i / HID, c = i % HID;
        float a = 0.f;
#pragma unroll
        for (int e = 0; e < E; ++e) a += rwl[e] * pw_w[((size_t)e * COUT + o) * HID + c];
        float inv3 = bn3_g[o] * rsqrtf(bn3_v[o] + EPS);
        wb[o * HID + c] = f2bf(a * inv3 * scl[c]);
    }
}

// ---------------- K6: pointwise GEMM (MFMA bf16) + BN3 shift + residual -> out ----------------
// staging widened: W tile uint4 (16B), H tile uint2 (8B, preserves 116-stride 2-way-only bfr banks)
__global__ __launch_bounds__(448) void k_pw_mfma(
    const __hip_bfloat16* __restrict__ hid, const unsigned short* __restrict__ wpw,  // [b][96][576] bf16
    const float* __restrict__ x,
    const float* __restrict__ bn3_g, const float* __restrict__ bn3_b,
    const float* __restrict__ bn3_m, const float* __restrict__ bn3_v,
    float* __restrict__ out) {
    int nc = blockIdx.x;  // 0..6
    int b = blockIdx.y;
    int tid = threadIdx.x;
    int lane = tid & 63, nf = tid >> 6;
    int col = lane & 15, g = lane >> 4;
    __shared__ unsigned short Wl[96 * 104];  // [m=96][k=96 pad 104]  (104 shorts = 208B, 16B-aligned rows)
    __shared__ unsigned short Ht[96 * 116];  // [k=96][px=112 pad 116] (116 shorts = 232B, 8B-aligned rows)
    __shared__ float inv3s[COUT], sh3s[COUT];
    if (tid < COUT) {
        float inv = bn3_g[tid] * rsqrtf(bn3_v[tid] + EPS);
        inv3s[tid] = inv;
        sh3s[tid] = bn3_b[tid] - bn3_m[tid] * inv;
    }
    const unsigned short* hb = (const unsigned short*)hid + (size_t)b * HID * NPIX + nc * 112;
    const unsigned short* wb = wpw + (size_t)b * COUT * HID;
    f32x4 acc[6];
#pragma unroll
    for (int m = 0; m < 6; ++m) acc[m] = (f32x4){0.f, 0.f, 0.f, 0.f};

    for (int ks = 0; ks < 6; ++ks) {
        __syncthreads();
        // stage W tile [96 m][96 k]: uint4 (8 shorts) — 1152 vec-copies
        for (int i = tid; i < 96 * 12; i += 448) {
            int m = i / 12, q = i % 12;
            *(uint4*)&Wl[m * 104 + 8 * q] = *(const uint4*)&wb[m * HID + ks * 96 + 8 * q];
        }
        // stage H tile [96 k][112 px]: uint2 (4 shorts) — 2688 vec-copies
        for (int i = tid; i < 96 * 28; i += 448) {
            int k = i / 28, q = i % 28;
            *(uint2*)&Ht[k * 116 + 4 * q] = *(const uint2*)&hb[((size_t)(ks * 96 + k)) * NPIX + 4 * q];
        }
        __syncthreads();
#pragma unroll
        for (int kk = 0; kk < 3; ++kk) {
            int k0 = kk * 32 + 8 * g;
            short8v bfr;
#pragma unroll
            for (int j = 0; j < 8; ++j) bfr[j] = (short)Ht[(k0 + j) * 116 + nf * 16 + col];
#pragma unroll
            for (int m = 0; m < 6; ++m) {
                short8v af = *(const short8v*)&Wl[(m * 16 + col) * 104 + kk * 32 + 8 * g];
                acc[m] = __builtin_amdgcn_mfma_f32_16x16x32_bf16(af, bfr, acc[m], 0, 0, 0);
            }
        }
    }
    int px = nc * 112 + nf * 16 + col;
#pragma unroll
    for (int m = 0; m < 6; ++m) {
#pragma unroll
        for (int r = 0; r < 4; ++r) {
            int oc = m * 16 + 4 * g + r;
            size_t off = ((size_t)b * COUT + oc) * NPIX + px;
            out[off] = acc[m][r] + sh3s[oc] + x[off];
        }
    }
}

extern "C" void kernel_launch(void* const* d_in, const int* in_sizes, int n_in,
                              void* d_out, int out_size, void* d_ws, size_t ws_size,
                              hipStream_t stream) {
    const float* x     = (const float*)d_in[0];
    const float* r_w1  = (const float*)d_in[1];
    const float* r_b1  = (const float*)d_in[2];
    const float* r_w2  = (const float*)d_in[3];
    const float* r_b2  = (const float*)d_in[4];
    const float* exp_w = (const float*)d_in[5];
    const float* bn1_g = (const float*)d_in[6];
    const float* bn1_b = (const float*)d_in[7];
    const float* bn1_m = (const float*)d_in[8];
    const float* bn1_v = (const float*)d_in[9];
    const float* dw_w  = (const float*)d_in[10];
    const float* bn2_g = (const float*)d_in[11];
    const float* bn2_b = (const float*)d_in[12];
    const float* bn2_m = (const float*)d_in[13];
    const float* bn2_v = (const float*)d_in[14];
    const float* se_w1 = (const float*)d_in[15];
    const float* se_b1 = (const float*)d_in[16];
    const float* se_w2 = (const float*)d_in[17];
    const float* se_b2 = (const float*)d_in[18];
    const float* pw_w  = (const float*)d_in[19];
    const float* bn3_g = (const float*)d_in[20];
    const float* bn3_b = (const float*)d_in[21];
    const float* bn3_m = (const float*)d_in[22];
    const float* bn3_v = (const float*)d_in[23];
    float* out = (float*)d_out;

    char* ws = (char*)d_ws;
    float* rw                 = (float*)(ws + 0);        // 1 KB
    float* pool               = (float*)(ws + 1024);     // 24 KB
    float* s                  = (float*)(ws + 26624);    // 147 KB
    unsigned short* exp_w_bf  = (unsigned short*)(ws + 174336);   // 110 KB
    unsigned short* wpw_bf    = (unsigned short*)(ws + 285184);   // 7.08 MB
    __hip_bfloat16* hid       = (__hip_bfloat16*)(ws + 7363328);  // 57.8 MB

    k_pool_wcvt<<<1536 + 216, 256, 0, stream>>>(x, pool, exp_w, exp_w_bf);
    k_mlp<<<1, 256, 0, stream>>>(pool, r_w1, r_b1, r_w2, r_b2, rw);
    k_expand_mfma<<<dim3(7, B), 256, 0, stream>>>(x, exp_w_bf, bn1_g, bn1_b, bn1_m, bn1_v, hid);
    k_dw<<<dim3(36, B), 448, 0, stream>>>(hid, rw, dw_w, bn2_g, bn2_b, bn2_m, bn2_v, s);
    k_se_wpw<<<dim3(6, B), 256, 0, stream>>>(s, se_w1, se_b1, se_w2, se_b2, rw, pw_w, bn3_g, bn3_v, wpw_bf);
    k_pw_mfma<<<dim3(7, B), 448, 0, stream>>>(hid, wpw_bf, x, bn3_g, bn3_b, bn3_m, bn3_v, out);
}

// Round 8
// 293.489 us; speedup vs baseline: 1.2319x; 1.0081x over previous
//
#include <hip/hip_runtime.h>
#include <hip/hip_bf16.h>
#include <math.h>

#define B 64
#define CIN 96
#define HH 28
#define WW 28
#define NPIX 784
#define E 4
#define HID 576
#define RED 24
#define RHID 24
#define COUT 96
#define EPS 1e-3f

typedef __attribute__((ext_vector_type(8))) short short8v;
typedef __attribute__((ext_vector_type(4))) float f32x4;

__device__ __forceinline__ float sigmoidf_(float v) { return 1.0f / (1.0f + __expf(-v)); }

__device__ __forceinline__ unsigned short f2bf(float v) {
    __hip_bfloat16 h = __float2bfloat16(v);
    return *reinterpret_cast<unsigned short*>(&h);
}

__device__ __forceinline__ float bf2f(unsigned short u) {
    unsigned int w = ((unsigned int)u) << 16;
    return *reinterpret_cast<float*>(&w);
}

// ---------------- K1a: pool (blocks 0..1535) ; exp_w->bf16 (blocks 1536..1751) ----------------
__global__ __launch_bounds__(256) void k_pool_wcvt(const float* __restrict__ x, float* __restrict__ pool,
                                                   const float* __restrict__ w, unsigned short* __restrict__ wb) {
    if (blockIdx.x < 1536) {
        int row = blockIdx.x * 4 + (threadIdx.x >> 6);  // b*CIN + c
        int lane = threadIdx.x & 63;
        const float4* xr = reinterpret_cast<const float4*>(x + (size_t)row * NPIX);
        float s = 0.f;
        for (int i = lane; i < 196; i += 64) {
            float4 v = xr[i];
            s += v.x + v.y + v.z + v.w;
        }
#pragma unroll
        for (int off = 32; off > 0; off >>= 1) s += __shfl_down(s, off);
        if (lane == 0) pool[row] = s * (1.0f / NPIX);
    } else {
        int i = (blockIdx.x - 1536) * 256 + threadIdx.x;
        wb[i] = f2bf(w[i]);
    }
}

// ---------------- K1b: MLP + softmax; 1 block, thread t = sample t ----------------
__global__ __launch_bounds__(256) void k_mlp(const float* __restrict__ pool,
                                             const float* __restrict__ r_w1, const float* __restrict__ r_b1,
                                             const float* __restrict__ r_w2, const float* __restrict__ r_b2,
                                             float* __restrict__ rw) {
    __shared__ float w1[RHID * CIN];
    __shared__ float b1s[RHID];
    __shared__ float w2[E * RHID];
    __shared__ float b2s[E];
    __shared__ float pl[B * CIN];
    int tid = threadIdx.x;
    for (int i = tid; i < RHID * CIN; i += 256) w1[i] = r_w1[i];
    if (tid < RHID) b1s[tid] = r_b1[tid];
    if (tid < E * RHID) w2[tid] = r_w2[tid];
    if (tid < E) b2s[tid] = r_b2[tid];
    for (int i = tid; i < B * CIN; i += 256) pl[i] = pool[i];
    __syncthreads();
    if (tid < B) {
        const float* p = pl + tid * CIN;
        float hdn[RHID];
#pragma unroll
        for (int r = 0; r < RHID; ++r) {
            float a = b1s[r];
            for (int c = 0; c < CIN; ++c) a += p[c] * w1[r * CIN + c];
            hdn[r] = fmaxf(a, 0.f);
        }
        float lg[E];
        float mx = -1e30f;
#pragma unroll
        for (int e = 0; e < E; ++e) {
            float a = b2s[e];
#pragma unroll
            for (int r = 0; r < RHID; ++r) a += hdn[r] * w2[e * RHID + r];
            lg[e] = a;
            mx = fmaxf(mx, a);
        }
        float den = 0.f;
#pragma unroll
        for (int e = 0; e < E; ++e) { lg[e] = __expf(lg[e] - mx); den += lg[e]; }
#pragma unroll
        for (int e = 0; e < E; ++e) rw[tid * E + e] = lg[e] / den;
    }
}

// ---------------- K3: expand GEMM (MFMA bf16) + BN1 + SiLU -> hid ----------------
// x tile stored TRANSPOSED [px=112][k=96 pad 104] -> B-fragment = one ds_read_b128.
__global__ __launch_bounds__(256) void k_expand_mfma(
    const float* __restrict__ x, const unsigned short* __restrict__ w_bf,  // [576][96] bf16
    const float* __restrict__ bn1_g, const float* __restrict__ bn1_b,
    const float* __restrict__ bn1_m, const float* __restrict__ bn1_v,
    __hip_bfloat16* __restrict__ hid) {
    int nc = blockIdx.x;  // 0..6
    int b = blockIdx.y;
    int tid = threadIdx.x;
    int lane = tid & 63, wv = tid >> 6;
    int col = lane & 15, g = lane >> 4;
    __shared__ unsigned short xt2[112 * 104];  // [px][k pad 104] bf16; 208B rows (16B-aligned)
    __shared__ float inv1s[HID], sh1s[HID];

    for (int i = tid; i < HID; i += 256) {
        float inv = bn1_g[i] * rsqrtf(bn1_v[i] + EPS);
        inv1s[i] = inv;
        sh1s[i] = bn1_b[i] - bn1_m[i] * inv;
    }
    // stage transposed: thread loads 4 channels at one pixel (coalesced), one ds_write_b64
    const float* xb = x + (size_t)b * CIN * NPIX + nc * 112;
    for (int i = tid; i < 24 * 112; i += 256) {
        int cg = i / 112, px = i % 112;
        const float* xp = xb + 4 * cg * NPIX + px;
        ushort4 s;
        s.x = f2bf(xp[0]);
        s.y = f2bf(xp[NPIX]);
        s.z = f2bf(xp[2 * NPIX]);
        s.w = f2bf(xp[3 * NPIX]);
        *reinterpret_cast<ushort4*>(&xt2[px * 104 + 4 * cg]) = s;
    }

    // hoist A-fragments (weights) into registers
    const short8v* wv8 = reinterpret_cast<const short8v*>(w_bf);
    short8v af[9][3];
#pragma unroll
    for (int mi = 0; mi < 9; ++mi) {
#pragma unroll
        for (int kk = 0; kk < 3; ++kk)
            af[mi][kk] = wv8[(((wv * 9 + mi) * 16 + col) * 96 + kk * 32 + 8 * g) >> 3];
    }
    __syncthreads();

    for (int nf = 0; nf < 7; ++nf) {
        int pcol = nf * 16 + col;
        short8v bfr[3];
#pragma unroll
        for (int kk = 0; kk < 3; ++kk)
            bfr[kk] = *(const short8v*)&xt2[pcol * 104 + kk * 32 + 8 * g];
        int px = nc * 112 + pcol;
#pragma unroll
        for (int mi = 0; mi < 9; ++mi) {
            int mb = (wv * 9 + mi) * 16;
            f32x4 acc = {0.f, 0.f, 0.f, 0.f};
#pragma unroll
            for (int kk = 0; kk < 3; ++kk)
                acc = __builtin_amdgcn_mfma_f32_16x16x32_bf16(af[mi][kk], bfr[kk], acc, 0, 0, 0);
#pragma unroll
            for (int r = 0; r < 4; ++r) {
                int oc = mb + 4 * g + r;
                float t = acc[r] * inv1s[oc] + sh1s[oc];
                float u = t * sigmoidf_(t);
                hid[((size_t)b * HID + oc) * NPIX + px] = __float2bfloat16(u);
            }
        }
    }
}

// ---------------- K4: depthwise 5x5, fp32 zero-halo LDS plane, 448 thr = 16ch x 28cols ----------------
#define CT 16
#define RSF 33                 // padded row stride (floats)
#define PCSF 1084              // channel stride (floats); 1084 % 32 == 28 -> exact 2-way wave banking
__global__ __launch_bounds__(448) void k_dw(
    __hip_bfloat16* __restrict__ hid, const float* __restrict__ rw,
    const float* __restrict__ dw_w,
    const float* __restrict__ bn2_g, const float* __restrict__ bn2_b,
    const float* __restrict__ bn2_m, const float* __restrict__ bn2_v,
    float* __restrict__ s_out) {
    int ct = blockIdx.x;  // 0..35
    int b = blockIdx.y;
    int tid = threadIdx.x;
    int cb = ct * CT;
    __shared__ float PF[CT * PCSF];  // 69.4 KB, zero halo
    __shared__ float kl[CT][25];
    __shared__ float ssum[CT];
    __hip_bfloat16* hb = hid + ((size_t)b * HID + cb) * NPIX;

    for (int i = tid; i < CT * PCSF; i += 448) PF[i] = 0.f;
    if (tid < CT) ssum[tid] = 0.f;
    __syncthreads();

    int ci = tid / 28, w = tid - ci * 28;
    {
        const unsigned int* src = reinterpret_cast<const unsigned int*>(hb) + ci * (NPIX / 2) + w * 14;
        float* dst = PF + ci * PCSF + (w + 2) * RSF + 2;
#pragma unroll
        for (int d = 0; d < 14; ++d) {
            unsigned int v = src[d];
            dst[2 * d]     = bf2f((unsigned short)(v & 0xffffu));
            dst[2 * d + 1] = bf2f((unsigned short)(v >> 16));
        }
    }
    {
        float rwl[E];
#pragma unroll
        for (int e = 0; e < E; ++e) rwl[e] = rw[b * E + e];
        for (int i = tid; i < CT * 25; i += 448) {
            int c2 = i / 25, j = i % 25;
            int c = cb + c2;
            float a = 0.f;
#pragma unroll
            for (int e = 0; e < E; ++e) a += rwl[e] * dw_w[((size_t)e * HID + c) * 25 + j];
            kl[c2][j] = a * (bn2_g[c] * rsqrtf(bn2_v[c] + EPS));
        }
    }
    __syncthreads();

    const float* Pc = PF + ci * PCSF + w;
    float k[25];
#pragma unroll
    for (int j = 0; j < 25; ++j) k[j] = kl[ci][j];
    int c = cb + ci;
    float inv2 = bn2_g[c] * rsqrtf(bn2_v[c] + EPS);
    float sh2 = bn2_b[c] - bn2_m[c] * inv2;
    unsigned short* hout = reinterpret_cast<unsigned short*>(hb) + ci * NPIX + w;

    float win[5][5];
#pragma unroll
    for (int i = 0; i < 5; ++i)
#pragma unroll
        for (int j = 0; j < 5; ++j) win[i][j] = Pc[i * RSF + j];

    float csum = 0.f;
#pragma unroll
    for (int h = 0; h < HH; ++h) {
        // 5 independent fmac chains (one per window row) -> tree add: breaks 25-deep serial chain
        float o0 = win[0][0] * k[0], o1 = win[1][0] * k[5], o2 = win[2][0] * k[10],
              o3 = win[3][0] * k[15], o4 = win[4][0] * k[20];
#pragma unroll
        for (int j = 1; j < 5; ++j) {
            o0 += win[0][j] * k[j];
            o1 += win[1][j] * k[5 + j];
            o2 += win[2][j] * k[10 + j];
            o3 += win[3][j] * k[15 + j];
            o4 += win[4][j] * k[20 + j];
        }
        float t = ((o0 + o1) + (o2 + o3)) + (o4 + sh2);
        float u = t * sigmoidf_(t);
        csum += u;
        hout[h * WW] = f2bf(u);
        if (h < HH - 1) {
#pragma unroll
            for (int i = 0; i < 4; ++i)
#pragma unroll
                for (int j = 0; j < 5; ++j) win[i][j] = win[i + 1][j];
#pragma unroll
            for (int j = 0; j < 5; ++j) win[4][j] = Pc[(h + 5) * RSF + j];
        }
    }
    atomicAdd(&ssum[ci], csum);
    __syncthreads();
    if (tid < CT) s_out[(size_t)b * HID + cb + tid] = ssum[tid] * (1.0f / NPIX);
}

// ---------------- K5: SE MLP (parallel dot) + wpw slice; grid (6, B) ----------------
__global__ __launch_bounds__(256) void k_se_wpw(
    const float* __restrict__ s, const float* __restrict__ se_w1,
    const float* __restrict__ se_b1, const float* __restrict__ se_w2,
    const float* __restrict__ se_b2, const float* __restrict__ rw,
    const float* __restrict__ pw_w,
    const float* __restrict__ bn3_g, const float* __restrict__ bn3_v,
    unsigned short* __restrict__ wpw) {
    int seg = blockIdx.x;  // 0..5 -> oc range
    int b = blockIdx.y;
    int tid = threadIdx.x;
    __shared__ float sl[HID];
    __shared__ float zl[RED];
    __shared__ float scl[HID];
    for (int i = tid; i < HID; i += 256) sl[i] = s[(size_t)b * HID + i];
    __syncthreads();
    if (tid < RED * 8) {
        int r = tid >> 3, l = tid & 7;
        float a = 0.f;
        for (int c = l; c < HID; c += 8) a += sl[c] * se_w1[r * HID + c];
        a += __shfl_down(a, 4, 8);
        a += __shfl_down(a, 2, 8);
        a += __shfl_down(a, 1, 8);
        if (l == 0) {
            a += se_b1[r];
            zl[r] = a * sigmoidf_(a);
        }
    }
    __syncthreads();
    for (int c = tid; c < HID; c += 256) {
        float a = se_b2[c];
#pragma unroll
        for (int r = 0; r < RED; ++r) a += zl[r] * se_w2[c * RED + r];
        scl[c] = sigmoidf_(a);
    }
    __syncthreads();
    float rwl[E];
#pragma unroll
    for (int e = 0; e < E; ++e) rwl[e] = rw[b * E + e];
    unsigned short* wb = wpw + (size_t)b * COUT * HID;
    for (int i = tid; i < 16 * HID; i += 256) {
        int o = seg * 16 + i / HID, c = i % HID;
        float a = 0.f;
#pragma unroll
        for (int e = 0; e < E; ++e) a += rwl[e] * pw_w[((size_t)e * COUT + o) * HID + c];
        float inv3 = bn3_g[o] * rsqrtf(bn3_v[o] + EPS);
        wb[o * HID + c] = f2bf(a * inv3 * scl[c]);
    }
}

// ---------------- K6: pointwise GEMM (MFMA bf16) + BN3 shift + residual -> out ----------------
// H tile stored TRANSPOSED [px=112][k=96 pad 104] -> B-fragment = one ds_read_b128.
__global__ __launch_bounds__(448) void k_pw_mfma(
    const __hip_bfloat16* __restrict__ hid, const unsigned short* __restrict__ wpw,  // [b][96][576] bf16
    const float* __restrict__ x,
    const float* __restrict__ bn3_g, const float* __restrict__ bn3_b,
    const float* __restrict__ bn3_m, const float* __restrict__ bn3_v,
    float* __restrict__ out) {
    int nc = blockIdx.x;  // 0..6
    int b = blockIdx.y;
    int tid = threadIdx.x;
    int lane = tid & 63, nf = tid >> 6;
    int col = lane & 15, g = lane >> 4;
    __shared__ unsigned short Wl[96 * 104];   // [m=96][k=96 pad 104]
    __shared__ unsigned short Ht2[112 * 104]; // [px=112][k=96 pad 104]
    __shared__ float inv3s[COUT], sh3s[COUT];
    if (tid < COUT) {
        float inv = bn3_g[tid] * rsqrtf(bn3_v[tid] + EPS);
        inv3s[tid] = inv;
        sh3s[tid] = bn3_b[tid] - bn3_m[tid] * inv;
    }
    const unsigned short* hb = (const unsigned short*)hid + (size_t)b * HID * NPIX + nc * 112;
    const unsigned short* wb = wpw + (size_t)b * COUT * HID;
    f32x4 acc[6];
#pragma unroll
    for (int m = 0; m < 6; ++m) acc[m] = (f32x4){0.f, 0.f, 0.f, 0.f};

    for (int ks = 0; ks < 6; ++ks) {
        __syncthreads();
        // stage W tile [96 m][96 k]: uint4 (8 shorts)
        for (int i = tid; i < 96 * 12; i += 448) {
            int m = i / 12, q = i % 12;
            *(uint4*)&Wl[m * 104 + 8 * q] = *(const uint4*)&wb[m * HID + ks * 96 + 8 * q];
        }
        // stage H tile transposed: thread loads 4 k-rows at one pixel (coalesced 2B runs), one b64 write
        for (int i = tid; i < 24 * 112; i += 448) {
            int kg = i / 112, px = i % 112;
            const unsigned short* hk = hb + (size_t)(ks * 96 + 4 * kg) * NPIX + px;
            ushort4 s;
            s.x = hk[0];
            s.y = hk[NPIX];
            s.z = hk[2 * NPIX];
            s.w = hk[3 * NPIX];
            *reinterpret_cast<ushort4*>(&Ht2[px * 104 + 4 * kg]) = s;
        }
        __syncthreads();
#pragma unroll
        for (int kk = 0; kk < 3; ++kk) {
            short8v bfr = *(const short8v*)&Ht2[(nf * 16 + col) * 104 + kk * 32 + 8 * g];
#pragma unroll
            for (int m = 0; m < 6; ++m) {
                short8v af = *(const short8v*)&Wl[(m * 16 + col) * 104 + kk * 32 + 8 * g];
                acc[m] = __builtin_amdgcn_mfma_f32_16x16x32_bf16(af, bfr, acc[m], 0, 0, 0);
            }
        }
    }
    int px = nc * 112 + nf * 16 + col;
#pragma unroll
    for (int m = 0; m < 6; ++m) {
#pragma unroll
        for (int r = 0; r < 4; ++r) {
            int oc = m * 16 + 4 * g + r;
            size_t off = ((size_t)b * COUT + oc) * NPIX + px;
            out[off] = acc[m][r] + sh3s[oc] + x[off];
        }
    }
}

extern "C" void kernel_launch(void* const* d_in, const int* in_sizes, int n_in,
                              void* d_out, int out_size, void* d_ws, size_t ws_size,
                              hipStream_t stream) {
    const float* x     = (const float*)d_in[0];
    const float* r_w1  = (const float*)d_in[1];
    const float* r_b1  = (const float*)d_in[2];
    const float* r_w2  = (const float*)d_in[3];
    const float* r_b2  = (const float*)d_in[4];
    const float* exp_w = (const float*)d_in[5];
    const float* bn1_g = (const float*)d_in[6];
    const float* bn1_b = (const float*)d_in[7];
    const float* bn1_m = (const float*)d_in[8];
    const float* bn1_v = (const float*)d_in[9];
    const float* dw_w  = (const float*)d_in[10];
    const float* bn2_g = (const float*)d_in[11];
    const float* bn2_b = (const float*)d_in[12];
    const float* bn2_m = (const float*)d_in[13];
    const float* bn2_v = (const float*)d_in[14];
    const float* se_w1 = (const float*)d_in[15];
    const float* se_b1 = (const float*)d_in[16];
    const float* se_w2 = (const float*)d_in[17];
    const float* se_b2 = (const float*)d_in[18];
    const float* pw_w  = (const float*)d_in[19];
    const float* bn3_g = (const float*)d_in[20];
    const float* bn3_b = (const float*)d_in[21];
    const float* bn3_m = (const float*)d_in[22];
    const float* bn3_v = (const float*)d_in[23];
    float* out = (float*)d_out;

    char* ws = (char*)d_ws;
    float* rw                 = (float*)(ws + 0);        // 1 KB
    float* pool               = (float*)(ws + 1024);     // 24 KB
    float* s                  = (float*)(ws + 26624);    // 147 KB
    unsigned short* exp_w_bf  = (unsigned short*)(ws + 174336);   // 110 KB
    unsigned short* wpw_bf    = (unsigned short*)(ws + 285184);   // 7.08 MB
    __hip_bfloat16* hid       = (__hip_bfloat16*)(ws + 7363328);  // 57.8 MB

    k_pool_wcvt<<<1536 + 216, 256, 0, stream>>>(x, pool, exp_w, exp_w_bf);
    k_mlp<<<1, 256, 0, stream>>>(pool, r_w1, r_b1, r_w2, r_b2, rw);
    k_expand_mfma<<<dim3(7, B), 256, 0, stream>>>(x, exp_w_bf, bn1_g, bn1_b, bn1_m, bn1_v, hid);
    k_dw<<<dim3(36, B), 448, 0, stream>>>(hid, rw, dw_w, bn2_g, bn2_b, bn2_m, bn2_v, s);
    k_se_wpw<<<dim3(6, B), 256, 0, stream>>>(s, se_w1, se_b1, se_w2, se_b2, rw, pw_w, bn3_g, bn3_v, wpw_bf);
    k_pw_mfma<<<dim3(7, B), 448, 0, stream>>>(hid, wpw_bf, x, bn3_g, bn3_b, bn3_m, bn3_v, out);
}

// Round 10
// 282.596 us; speedup vs baseline: 1.2793x; 1.0385x over previous
//
#include <hip/hip_runtime.h>
#include <hip/hip_bf16.h>
#include <math.h>

#define B 64
#define CIN 96
#define HH 28
#define WW 28
#define NPIX 784
#define E 4
#define HID 576
#define RED 24
#define RHID 24
#define COUT 96
#define EPS 1e-3f

typedef __attribute__((ext_vector_type(8))) short short8v;
typedef __attribute__((ext_vector_type(4))) float f32x4;

__device__ __forceinline__ float sigmoidf_(float v) { return 1.0f / (1.0f + __expf(-v)); }

__device__ __forceinline__ unsigned short f2bf(float v) {
    __hip_bfloat16 h = __float2bfloat16(v);
    return *reinterpret_cast<unsigned short*>(&h);
}

__device__ __forceinline__ float bf2f(unsigned short u) {
    unsigned int w = ((unsigned int)u) << 16;
    return *reinterpret_cast<float*>(&w);
}

// ---------------- K1a: pool (0..1535) | exp_w->bf16 (1536..1751) | x transpose -> x_t[b][px][96] (1752..2199) ----------------
__global__ __launch_bounds__(256) void k_pool_wcvt(const float* __restrict__ x, float* __restrict__ pool,
                                                   const float* __restrict__ w, unsigned short* __restrict__ wb,
                                                   unsigned short* __restrict__ x_t) {
    __shared__ unsigned short xt2[112 * 104];
    int tid = threadIdx.x;
    if (blockIdx.x < 1536) {
        int row = blockIdx.x * 4 + (tid >> 6);  // b*CIN + c
        int lane = tid & 63;
        const float4* xr = reinterpret_cast<const float4*>(x + (size_t)row * NPIX);
        float s = 0.f;
        for (int i = lane; i < 196; i += 64) {
            float4 v = xr[i];
            s += v.x + v.y + v.z + v.w;
        }
#pragma unroll
        for (int off = 32; off > 0; off >>= 1) s += __shfl_down(s, off);
        if (lane == 0) pool[row] = s * (1.0f / NPIX);
    } else if (blockIdx.x < 1752) {
        int i = (blockIdx.x - 1536) * 256 + tid;  // 216*256 == HID*CIN
        wb[i] = f2bf(w[i]);
    } else {
        // transpose one (b, 112-px chunk): x[b][96c][112px] -> x_t[b][px][96c] bf16
        int bid = blockIdx.x - 1752;   // 0..447
        int nc = bid % 7, b = bid / 7;
        const float* xb = x + (size_t)b * CIN * NPIX + nc * 112;
        for (int i = tid; i < 24 * 112; i += 256) {
            int cg = i / 112, px = i % 112;
            const float* xp = xb + 4 * cg * NPIX + px;
            ushort4 s4;
            s4.x = f2bf(xp[0]);
            s4.y = f2bf(xp[NPIX]);
            s4.z = f2bf(xp[2 * NPIX]);
            s4.w = f2bf(xp[3 * NPIX]);
            *reinterpret_cast<ushort4*>(&xt2[px * 104 + 4 * cg]) = s4;
        }
        __syncthreads();
        unsigned short* xo = x_t + ((size_t)b * NPIX + nc * 112) * 96;
        for (int i = tid; i < 112 * 24; i += 256) {
            int px = i / 24, q = i % 24;
            *reinterpret_cast<ushort4*>(&xo[px * 96 + 4 * q]) =
                *reinterpret_cast<const ushort4*>(&xt2[px * 104 + 4 * q]);
        }
    }
}

// ---------------- K1b: MLP + softmax; 1 block, thread t = sample t ----------------
__global__ __launch_bounds__(256) void k_mlp(const float* __restrict__ pool,
                                             const float* __restrict__ r_w1, const float* __restrict__ r_b1,
                                             const float* __restrict__ r_w2, const float* __restrict__ r_b2,
                                             float* __restrict__ rw) {
    __shared__ float w1[RHID * CIN];
    __shared__ float b1s[RHID];
    __shared__ float w2[E * RHID];
    __shared__ float b2s[E];
    __shared__ float pl[B * CIN];
    int tid = threadIdx.x;
    for (int i = tid; i < RHID * CIN; i += 256) w1[i] = r_w1[i];
    if (tid < RHID) b1s[tid] = r_b1[tid];
    if (tid < E * RHID) w2[tid] = r_w2[tid];
    if (tid < E) b2s[tid] = r_b2[tid];
    for (int i = tid; i < B * CIN; i += 256) pl[i] = pool[i];
    __syncthreads();
    if (tid < B) {
        const float* p = pl + tid * CIN;
        float hdn[RHID];
#pragma unroll
        for (int r = 0; r < RHID; ++r) {
            float a = b1s[r];
            for (int c = 0; c < CIN; ++c) a += p[c] * w1[r * CIN + c];
            hdn[r] = fmaxf(a, 0.f);
        }
        float lg[E];
        float mx = -1e30f;
#pragma unroll
        for (int e = 0; e < E; ++e) {
            float a = b2s[e];
#pragma unroll
            for (int r = 0; r < RHID; ++r) a += hdn[r] * w2[e * RHID + r];
            lg[e] = a;
            mx = fmaxf(mx, a);
        }
        float den = 0.f;
#pragma unroll
        for (int e = 0; e < E; ++e) { lg[e] = __expf(lg[e] - mx); den += lg[e]; }
#pragma unroll
        for (int e = 0; e < E; ++e) rw[tid * E + e] = lg[e] / den;
    }
}

// ---------------- K_EXDW: fused expand-GEMM (MFMA) -> LDS plane -> depthwise 5x5 + BN2 + SiLU + means ----------------
// block = (16-ch tile, sample). Phase 1: C[16oc][784px] = W16x96 . x_t^T, BN1+SiLU, scatter to fp32 halo plane.
// Phase 2: identical to verified r8 dw conv. hid is written ONCE (dw output), never round-tripped.
#define CT 16
#define RSF 33                 // plane row stride (floats)
#define PCSF 1084              // plane channel stride (floats); 1084 % 32 == 28 -> 2-way wave banking
__global__ __launch_bounds__(448) void k_exdw(
    const unsigned short* __restrict__ x_t,   // [b][px][96] bf16
    const unsigned short* __restrict__ w_bf,  // [576][96] bf16
    const float* __restrict__ bn1_g, const float* __restrict__ bn1_b,
    const float* __restrict__ bn1_m, const float* __restrict__ bn1_v,
    const float* __restrict__ rw, const float* __restrict__ dw_w,
    const float* __restrict__ bn2_g, const float* __restrict__ bn2_b,
    const float* __restrict__ bn2_m, const float* __restrict__ bn2_v,
    __hip_bfloat16* __restrict__ hid, float* __restrict__ s_out) {
    int ct = blockIdx.x;  // 0..35
    int b = blockIdx.y;
    int tid = threadIdx.x;
    int lane = tid & 63, wv = tid >> 6;
    int col = lane & 15, g = lane >> 4;
    int cb = ct * CT;
    __shared__ float PF[CT * PCSF];  // 69.4 KB zero-halo plane
    __shared__ float kl[CT][25];
    __shared__ float ssum[CT];
    __shared__ float inv1s[CT], sh1s[CT];

    // phase 0: zero plane + BN1 fold
    for (int i = tid; i < CT * PCSF; i += 448) PF[i] = 0.f;
    if (tid < CT) {
        ssum[tid] = 0.f;
        int oc = cb + tid;
        float inv = bn1_g[oc] * rsqrtf(bn1_v[oc] + EPS);
        inv1s[tid] = inv;
        sh1s[tid] = bn1_b[oc] - bn1_m[oc] * inv;
    }
    __syncthreads();

    // phase 1a: expand MFMA -> plane (per wave: 7 n-frags x 3 k-steps)
    {
        const short8v* wv8 = reinterpret_cast<const short8v*>(w_bf);
        short8v af[3];
#pragma unroll
        for (int kk = 0; kk < 3; ++kk)
            af[kk] = wv8[(((size_t)(cb + col)) * 96 + kk * 32 + 8 * g) >> 3];
        const unsigned short* xtb = x_t + (size_t)b * NPIX * 96;
        for (int nf = wv; nf < 49; nf += 7) {
            int px = nf * 16 + col;
            f32x4 acc = {0.f, 0.f, 0.f, 0.f};
#pragma unroll
            for (int kk = 0; kk < 3; ++kk) {
                short8v bfr = *(const short8v*)&xtb[(size_t)px * 96 + kk * 32 + 8 * g];
                acc = __builtin_amdgcn_mfma_f32_16x16x32_bf16(af[kk], bfr, acc, 0, 0, 0);
            }
            int h = px / 28, w_ = px - 28 * h;
            float* pc = &PF[(h + 2) * RSF + (w_ + 2)];
#pragma unroll
            for (int r = 0; r < 4; ++r) {
                int ci = 4 * g + r;
                float t = acc[r] * inv1s[ci] + sh1s[ci];
                pc[ci * PCSF] = t * sigmoidf_(t);
            }
        }
    }
    // phase 1b: expert-aggregated dw kernels (BN2 scale folded)
    {
        float rwl[E];
#pragma unroll
        for (int e = 0; e < E; ++e) rwl[e] = rw[b * E + e];
        for (int i = tid; i < CT * 25; i += 448) {
            int c2 = i / 25, j = i % 25;
            int c = cb + c2;
            float a = 0.f;
#pragma unroll
            for (int e = 0; e < E; ++e) a += rwl[e] * dw_w[((size_t)e * HID + c) * 25 + j];
            kl[c2][j] = a * (bn2_g[c] * rsqrtf(bn2_v[c] + EPS));
        }
    }
    __syncthreads();

    // phase 2: depthwise conv (identical to verified r8 structure)
    int ci = tid / 28, w = tid - ci * 28;
    const float* Pc = PF + ci * PCSF + w;
    float k[25];
#pragma unroll
    for (int j = 0; j < 25; ++j) k[j] = kl[ci][j];
    int c = cb + ci;
    float inv2 = bn2_g[c] * rsqrtf(bn2_v[c] + EPS);
    float sh2 = bn2_b[c] - bn2_m[c] * inv2;
    __hip_bfloat16* hb = hid + ((size_t)b * HID + cb) * NPIX;
    unsigned short* hout = reinterpret_cast<unsigned short*>(hb) + ci * NPIX + w;

    float win[5][5];
#pragma unroll
    for (int i = 0; i < 5; ++i)
#pragma unroll
        for (int j = 0; j < 5; ++j) win[i][j] = Pc[i * RSF + j];

    float csum = 0.f;
#pragma unroll
    for (int h = 0; h < HH; ++h) {
        float o0 = win[0][0] * k[0], o1 = win[1][0] * k[5], o2 = win[2][0] * k[10],
              o3 = win[3][0] * k[15], o4 = win[4][0] * k[20];
#pragma unroll
        for (int j = 1; j < 5; ++j) {
            o0 += win[0][j] * k[j];
            o1 += win[1][j] * k[5 + j];
            o2 += win[2][j] * k[10 + j];
            o3 += win[3][j] * k[15 + j];
            o4 += win[4][j] * k[20 + j];
        }
        float t = ((o0 + o1) + (o2 + o3)) + (o4 + sh2);
        float u = t * sigmoidf_(t);
        csum += u;
        hout[h * WW] = f2bf(u);
        if (h < HH - 1) {
#pragma unroll
            for (int i = 0; i < 4; ++i)
#pragma unroll
                for (int j = 0; j < 5; ++j) win[i][j] = win[i + 1][j];
#pragma unroll
            for (int j = 0; j < 5; ++j) win[4][j] = Pc[(h + 5) * RSF + j];
        }
    }
    atomicAdd(&ssum[ci], csum);
    __syncthreads();
    if (tid < CT) s_out[(size_t)b * HID + cb + tid] = ssum[tid] * (1.0f / NPIX);
}

// ---------------- K5: SE MLP (parallel dot) + wpw slice; grid (6, B) ----------------
__global__ __launch_bounds__(256) void k_se_wpw(
    const float* __restrict__ s, const float* __restrict__ se_w1,
    const float* __restrict__ se_b1, const float* __restrict__ se_w2,
    const float* __restrict__ se_b2, const float* __restrict__ rw,
    const float* __restrict__ pw_w,
    const float* __restrict__ bn3_g, const float* __restrict__ bn3_v,
    unsigned short* __restrict__ wpw) {
    int seg = blockIdx.x;  // 0..5 -> oc range
    int b = blockIdx.y;
    int tid = threadIdx.x;
    __shared__ float sl[HID];
    __shared__ float zl[RED];
    __shared__ float scl[HID];
    for (int i = tid; i < HID; i += 256) sl[i] = s[(size_t)b * HID + i];
    __syncthreads();
    if (tid < RED * 8) {
        int r = tid >> 3, l = tid & 7;
        float a = 0.f;
        for (int c = l; c < HID; c += 8) a += sl[c] * se_w1[r * HID + c];
        a += __shfl_down(a, 4, 8);
        a += __shfl_down(a, 2, 8);
        a += __shfl_down(a, 1, 8);
        if (l == 0) {
            a += se_b1[r];
            zl[r] = a * sigmoidf_(a);
        }
    }
    __syncthreads();
    for (int c = tid; c < HID; c += 256) {
        float a = se_b2[c];
#pragma unroll
        for (int r = 0; r < RED; ++r) a += zl[r] * se_w2[c * RED + r];
        scl[c] = sigmoidf_(a);
    }
    __syncthreads();
    float rwl[E];
#pragma unroll
    for (int e = 0; e < E; ++e) rwl[e] = rw[b * E + e];
    unsigned short* wb = wpw + (size_t)b * COUT * HID;
    for (int i = tid; i < 16 * HID; i += 256) {
        int o = seg * 16 + i / HID, c = i % HID;
        float a = 0.f;
#pragma unroll
        for (int e = 0; e < E; ++e) a += rwl[e] * pw_w[((size_t)e * COUT + o) * HID + c];
        float inv3 = bn3_g[o] * rsqrtf(bn3_v[o] + EPS);
        wb[o * HID + c] = f2bf(a * inv3 * scl[c]);
    }
}

// ---------------- K6: pointwise GEMM (MFMA bf16) + BN3 shift + residual -> out ----------------
__global__ __launch_bounds__(448) void k_pw_mfma(
    const __hip_bfloat16* __restrict__ hid, const unsigned short* __restrict__ wpw,  // [b][96][576] bf16
    const float* __restrict__ x,
    const float* __restrict__ bn3_g, const float* __restrict__ bn3_b,
    const float* __restrict__ bn3_m, const float* __restrict__ bn3_v,
    float* __restrict__ out) {
    int nc = blockIdx.x;  // 0..6
    int b = blockIdx.y;
    int tid = threadIdx.x;
    int lane = tid & 63, nf = tid >> 6;
    int col = lane & 15, g = lane >> 4;
    __shared__ unsigned short Wl[96 * 104];   // [m=96][k=96 pad 104]
    __shared__ unsigned short Ht2[112 * 104]; // [px=112][k=96 pad 104]
    __shared__ float inv3s[COUT], sh3s[COUT];
    if (tid < COUT) {
        float inv = bn3_g[tid] * rsqrtf(bn3_v[tid] + EPS);
        inv3s[tid] = inv;
        sh3s[tid] = bn3_b[tid] - bn3_m[tid] * inv;
    }
    const unsigned short* hb = (const unsigned short*)hid + (size_t)b * HID * NPIX + nc * 112;
    const unsigned short* wb = wpw + (size_t)b * COUT * HID;
    f32x4 acc[6];
#pragma unroll
    for (int m = 0; m < 6; ++m) acc[m] = (f32x4){0.f, 0.f, 0.f, 0.f};

    for (int ks = 0; ks < 6; ++ks) {
        __syncthreads();
        for (int i = tid; i < 96 * 12; i += 448) {
            int m = i / 12, q = i % 12;
            *(uint4*)&Wl[m * 104 + 8 * q] = *(const uint4*)&wb[m * HID + ks * 96 + 8 * q];
        }
        for (int i = tid; i < 24 * 112; i += 448) {
            int kg = i / 112, px = i % 112;
            const unsigned short* hk = hb + (size_t)(ks * 96 + 4 * kg) * NPIX + px;
            ushort4 s;
            s.x = hk[0];
            s.y = hk[NPIX];
            s.z = hk[2 * NPIX];
            s.w = hk[3 * NPIX];
            *reinterpret_cast<ushort4*>(&Ht2[px * 104 + 4 * kg]) = s;
        }
        __syncthreads();
#pragma unroll
        for (int kk = 0; kk < 3; ++kk) {
            short8v bfr = *(const short8v*)&Ht2[(nf * 16 + col) * 104 + kk * 32 + 8 * g];
#pragma unroll
            for (int m = 0; m < 6; ++m) {
                short8v af = *(const short8v*)&Wl[(m * 16 + col) * 104 + kk * 32 + 8 * g];
                acc[m] = __builtin_amdgcn_mfma_f32_16x16x32_bf16(af, bfr, acc[m], 0, 0, 0);
            }
        }
    }
    int px = nc * 112 + nf * 16 + col;
#pragma unroll
    for (int m = 0; m < 6; ++m) {
#pragma unroll
        for (int r = 0; r < 4; ++r) {
            int oc = m * 16 + 4 * g + r;
            size_t off = ((size_t)b * COUT + oc) * NPIX + px;
            out[off] = acc[m][r] + sh3s[oc] + x[off];
        }
    }
}

extern "C" void kernel_launch(void* const* d_in, const int* in_sizes, int n_in,
                              void* d_out, int out_size, void* d_ws, size_t ws_size,
                              hipStream_t stream) {
    const float* x     = (const float*)d_in[0];
    const float* r_w1  = (const float*)d_in[1];
    const float* r_b1  = (const float*)d_in[2];
    const float* r_w2  = (const float*)d_in[3];
    const float* r_b2  = (const float*)d_in[4];
    const float* exp_w = (const float*)d_in[5];
    const float* bn1_g = (const float*)d_in[6];
    const float* bn1_b = (const float*)d_in[7];
    const float* bn1_m = (const float*)d_in[8];
    const float* bn1_v = (const float*)d_in[9];
    const float* dw_w  = (const float*)d_in[10];
    const float* bn2_g = (const float*)d_in[11];
    const float* bn2_b = (const float*)d_in[12];
    const float* bn2_m = (const float*)d_in[13];
    const float* bn2_v = (const float*)d_in[14];
    const float* se_w1 = (const float*)d_in[15];
    const float* se_b1 = (const float*)d_in[16];
    const float* se_w2 = (const float*)d_in[17];
    const float* se_b2 = (const float*)d_in[18];
    const float* pw_w  = (const float*)d_in[19];
    const float* bn3_g = (const float*)d_in[20];
    const float* bn3_b = (const float*)d_in[21];
    const float* bn3_m = (const float*)d_in[22];
    const float* bn3_v = (const float*)d_in[23];
    float* out = (float*)d_out;

    char* ws = (char*)d_ws;
    float* rw                 = (float*)(ws + 0);        // 1 KB
    float* pool               = (float*)(ws + 1024);     // 24 KB
    float* s                  = (float*)(ws + 26624);    // 147 KB
    unsigned short* exp_w_bf  = (unsigned short*)(ws + 174336);   // 110 KB
    unsigned short* wpw_bf    = (unsigned short*)(ws + 285184);   // 7.08 MB
    unsigned short* x_t       = (unsigned short*)(ws + 7363328);  // 9.63 MB
    __hip_bfloat16* hid       = (__hip_bfloat16*)(ws + 16997120); // 57.8 MB (single-trip now)

    k_pool_wcvt<<<1536 + 216 + 448, 256, 0, stream>>>(x, pool, exp_w, exp_w_bf, x_t);
    k_mlp<<<1, 256, 0, stream>>>(pool, r_w1, r_b1, r_w2, r_b2, rw);
    k_exdw<<<dim3(36, B), 448, 0, stream>>>(x_t, exp_w_bf, bn1_g, bn1_b, bn1_m, bn1_v,
                                            rw, dw_w, bn2_g, bn2_b, bn2_m, bn2_v, hid, s);
    k_se_wpw<<<dim3(6, B), 256, 0, stream>>>(s, se_w1, se_b1, se_w2, se_b2, rw, pw_w, bn3_g, bn3_v, wpw_bf);
    k_pw_mfma<<<dim3(7, B), 448, 0, stream>>>(hid, wpw_bf, x, bn3_g, bn3_b, bn3_m, bn3_v, out);
}